// Round 4
// baseline (876.977 us; speedup 1.0000x reference)
//
#include <hip/hip_runtime.h>

typedef unsigned short ushort_t;
typedef __bf16 bf16x8 __attribute__((ext_vector_type(8)));
typedef float f32x4 __attribute__((ext_vector_type(4)));

#define N_TOKENS 4096
#define D_MODEL  1024
#define D_HIDDEN 16384
#define TOPK     64
#define DELTA    0.01f   // ~11 sigma of bf16-GEMM z error (sigma ~ 9e-4)
#define RCAP     128     // max refine candidates per row

__device__ __forceinline__ ushort_t f2bf(float f) {
  union { float f; unsigned u; } c; c.f = f;
  unsigned x = c.u;
  unsigned r = (x + 0x7FFFu + ((x >> 16) & 1u)) >> 16;  // RNE
  return (ushort_t)r;
}

typedef __attribute__((address_space(1))) void GV;
typedef __attribute__((address_space(3))) void LV;
__device__ __forceinline__ void llds16(const void* g, void* l) {
  __builtin_amdgcn_global_load_lds((GV*)g, (LV*)l, 16, 0, 0);
}

// ---------------------------------------------------------------------------
// Kernel 0: cast x fp32 [M][K] -> bf16 [M][K]
// ---------------------------------------------------------------------------
__global__ __launch_bounds__(256) void cast_x_kernel(
    const float* __restrict__ in, ushort_t* __restrict__ out) {
  const int i = (blockIdx.x * 256 + threadIdx.x) * 4;
  float4 v = *(const float4*)&in[i];
  ushort4 o;
  o.x = f2bf(v.x); o.y = f2bf(v.y); o.z = f2bf(v.z); o.w = f2bf(v.w);
  *(ushort4*)&out[i] = o;
}

// ---------------------------------------------------------------------------
// Kernel 1: W_enc fp32 [D_MODEL][D_HIDDEN] -> transposed bf16 WT [H][K]
//           AND transposed fp32 WT32 [H][K] (exact copy for refine).
// ---------------------------------------------------------------------------
__global__ __launch_bounds__(256) void transpose_cast_kernel(
    const float* __restrict__ in, ushort_t* __restrict__ outb,
    float* __restrict__ out32) {
  __shared__ float tile[64][68];
  const int tid = threadIdx.x;
  const int n0 = blockIdx.x * 64;   // hidden dim
  const int k0 = blockIdx.y * 64;   // model dim
#pragma unroll
  for (int i = 0; i < 4; ++i) {
    int e = i * 256 + tid;
    int kk = e >> 4;
    int nn = (e & 15) * 4;
    float4 v = *(const float4*)&in[(size_t)(k0 + kk) * D_HIDDEN + n0 + nn];
    tile[kk][nn + 0] = v.x;
    tile[kk][nn + 1] = v.y;
    tile[kk][nn + 2] = v.z;
    tile[kk][nn + 3] = v.w;
  }
  __syncthreads();
#pragma unroll
  for (int i = 0; i < 4; ++i) {
    int e = i * 256 + tid;
    int nn = e >> 4;
    int kk = (e & 15) * 4;
    float4 f;
    f.x = tile[kk + 0][nn];
    f.y = tile[kk + 1][nn];
    f.z = tile[kk + 2][nn];
    f.w = tile[kk + 3][nn];
    *(float4*)&out32[(size_t)(n0 + nn) * D_MODEL + k0 + kk] = f;
    ushort4 b;
    b.x = f2bf(f.x); b.y = f2bf(f.y); b.z = f2bf(f.z); b.w = f2bf(f.w);
    *(ushort4*)&outb[(size_t)(n0 + nn) * D_MODEL + k0 + kk] = b;
  }
}

// ---------------------------------------------------------------------------
// Kernel 2: Z~ = relu(x @ W_enc + b_enc) in bf16 MFMA, fp32 out (m97 128x128).
// ---------------------------------------------------------------------------
__global__ __launch_bounds__(256) void encode_gemm(
    const ushort_t* __restrict__ X, const ushort_t* __restrict__ WT,
    const float* __restrict__ benc, float* __restrict__ Z) {
  __shared__ ushort_t As[128 * 32];
  __shared__ ushort_t Bs[128 * 32];
  const int tid  = threadIdx.x;
  const int wave = tid >> 6, lane = tid & 63;
  const int m0 = blockIdx.y * 128;
  const int n0 = blockIdx.x * 128;
  const int wm = (wave >> 1) * 64;
  const int wn = (wave & 1) * 64;
  const int lr = lane >> 2;
  const int lk = (lane & 3) * 8;

  f32x4 acc[4][4];
#pragma unroll
  for (int i = 0; i < 4; ++i)
#pragma unroll
    for (int j = 0; j < 4; ++j) acc[i][j] = (f32x4){0.f, 0.f, 0.f, 0.f};

  for (int k0 = 0; k0 < D_MODEL; k0 += 32) {
    __syncthreads();
#pragma unroll
    for (int c = 0; c < 2; ++c) {
      const int chunk = c * 4 + wave;
      const int m = chunk * 16 + lr;
      llds16(&X [(size_t)(m0 + m) * D_MODEL + k0 + lk], &As[chunk * 512]);
      llds16(&WT[(size_t)(n0 + m) * D_MODEL + k0 + lk], &Bs[chunk * 512]);
    }
    __syncthreads();
    bf16x8 af[4], bfr[4];
#pragma unroll
    for (int t = 0; t < 4; ++t) {
      af[t]  = *(const bf16x8*)&As[(wm + t * 16 + (lane & 15)) * 32 + (lane >> 4) * 8];
      bfr[t] = *(const bf16x8*)&Bs[(wn + t * 16 + (lane & 15)) * 32 + (lane >> 4) * 8];
    }
#pragma unroll
    for (int mt = 0; mt < 4; ++mt)
#pragma unroll
      for (int nt = 0; nt < 4; ++nt)
        acc[mt][nt] = __builtin_amdgcn_mfma_f32_16x16x32_bf16(
            af[mt], bfr[nt], acc[mt][nt], 0, 0, 0);
  }

  const int col_base = n0 + wn + (lane & 15);
  const int row_base = m0 + wm + (lane >> 4) * 4;
#pragma unroll
  for (int nt = 0; nt < 4; ++nt) {
    const float bias = benc[col_base + nt * 16];
#pragma unroll
    for (int mt = 0; mt < 4; ++mt) {
#pragma unroll
      for (int r = 0; r < 4; ++r) {
        float v = acc[mt][nt][r] + bias;
        v = fmaxf(v, 0.0f);
        Z[(size_t)(row_base + mt * 16 + r) * D_HIDDEN + col_base + nt * 16] = v;
      }
    }
  }
}

// ---------------------------------------------------------------------------
// Kernel 3: top-64 with exact fp64 boundary resolution.
// Phase A: histogram (top-12 bits) -> threshold bin. Phase B: exact z~ 64th
// value v64. Phase C: sure (z~ > v64+DELTA) emitted; |z~-v64|<=DELTA refined.
// Phase D: exact fp64 dot from fp32 x row + fp32 WT32 row. Phase E: rank
// refined by (value desc, index asc), fill remaining slots.
// ---------------------------------------------------------------------------
__global__ __launch_bounds__(256) void topk_refine_kernel(
    const float* __restrict__ Z, const float* __restrict__ x32,
    const float* __restrict__ WT32, const float* __restrict__ benc,
    float* __restrict__ vals, int* __restrict__ idxs) {
  __shared__ int    hist[2048];
  __shared__ float  cval[1024];
  __shared__ int    cidx[1024];
  __shared__ int    tsum[256], suff[256];
  __shared__ float  xrow[1024];
  __shared__ int    ridx[RCAP];
  __shared__ double rex[RCAP];
  __shared__ double redpart[RCAP * 4];
  __shared__ int    sTbin, sAbove, selCount, candCount, refCount;
  __shared__ float  sV64;
  const int tid  = threadIdx.x;
  const int wave = tid >> 6, lane = tid & 63;
  const int row  = blockIdx.x;
  const float* zr = Z + (size_t)row * D_HIDDEN;

  float v[64];
#pragma unroll
  for (int i = 0; i < 64; ++i) v[i] = zr[tid + i * 256];
  *(float4*)&xrow[tid * 4] = *(const float4*)&x32[(size_t)row * D_MODEL + tid * 4];
#pragma unroll
  for (int i = 0; i < 8; ++i) hist[tid * 8 + i] = 0;
  if (tid == 0) { selCount = 0; candCount = 0; refCount = 0; }
  __syncthreads();
#pragma unroll
  for (int i = 0; i < 64; ++i)
    atomicAdd(&hist[__float_as_uint(v[i]) >> 20], 1);
  __syncthreads();
  int s = 0;
#pragma unroll
  for (int i = 0; i < 8; ++i) s += hist[tid * 8 + i];
  tsum[tid] = s;
  __syncthreads();
  if (tid == 0) {
    int run = 0;
    for (int t = 255; t >= 0; --t) { suff[t] = run; run += tsum[t]; }
  }
  __syncthreads();
  {
    int cum = suff[tid];
    for (int key = tid * 8 + 7; key >= tid * 8; --key) {
      int h = hist[key];
      if (cum < TOPK && cum + h >= TOPK) { sTbin = key; sAbove = cum; }
      cum += h;
    }
  }
  __syncthreads();
  const int Tbin = sTbin, nAbove = sAbove;

  if (Tbin == 0) {  // degenerate: <64 positive activations (never for this data)
#pragma unroll
    for (int i = 0; i < 64; ++i) {
      if ((int)(__float_as_uint(v[i]) >> 20) > 0) {
        int p = atomicAdd(&selCount, 1);
        if (p < TOPK) { vals[row * 64 + p] = v[i]; idxs[row * 64 + p] = tid + i * 256; }
      }
    }
    __syncthreads();
    for (int p2 = min(selCount, TOPK) + tid; p2 < TOPK; p2 += 256) {
      vals[row * 64 + p2] = 0.0f; idxs[row * 64 + p2] = 0;
    }
    return;
  }

  // Phase B: exact z~ 64th value (in-bin rank by value desc, index asc)
#pragma unroll
  for (int i = 0; i < 64; ++i) {
    if ((int)(__float_as_uint(v[i]) >> 20) == Tbin) {
      int c = atomicAdd(&candCount, 1);
      if (c < 1024) { cval[c] = v[i]; cidx[c] = tid + i * 256; }
    }
  }
  __syncthreads();
  {
    const int r  = TOPK - nAbove;            // >= 1
    const int nc = min(candCount, 1024);
    for (int j = tid; j < nc; j += 256) {
      float vj = cval[j]; int ij = cidx[j];
      int rank = 0;
      for (int j2 = 0; j2 < nc; ++j2) {
        float v2 = cval[j2];
        rank += (v2 > vj) || (v2 == vj && cidx[j2] < ij);
      }
      if (rank == r - 1) sV64 = vj;
    }
  }
  __syncthreads();
  const float v64 = sV64;

  // Phase C: classify by value
#pragma unroll
  for (int i = 0; i < 64; ++i) {
    if (v[i] > v64 + DELTA) {
      int p = atomicAdd(&selCount, 1);
      vals[row * 64 + p] = v[i];
      idxs[row * 64 + p] = tid + i * 256;
    } else if (v[i] >= v64 - DELTA) {
      int c = atomicAdd(&refCount, 1);
      if (c < RCAP) ridx[c] = tid + i * 256;
    }
  }
  __syncthreads();
  const int nS = selCount;
  const int nR = min(refCount, RCAP);
  const int rNeed = TOPK - nS;   // >= 1

  // Phase D: exact fp64 dots for refine candidates
  for (int c = 0; c < nR; ++c) {
    const int j = ridx[c];
    const float* wr = &WT32[(size_t)j * D_MODEL];
    double part = 0.0;
#pragma unroll
    for (int u = 0; u < 4; ++u)
      part += (double)xrow[tid * 4 + u] * (double)wr[tid * 4 + u];
#pragma unroll
    for (int off = 32; off > 0; off >>= 1) part += __shfl_down(part, off, 64);
    if (lane == 0) redpart[c * 4 + wave] = part;
  }
  __syncthreads();
  for (int c = tid; c < nR; c += 256) {
    double d = redpart[c * 4] + redpart[c * 4 + 1] + redpart[c * 4 + 2] + redpart[c * 4 + 3];
    d += (double)benc[ridx[c]];
    rex[c] = d > 0.0 ? d : 0.0;
  }
  __syncthreads();

  // Phase E: rank refined, take top rNeed
  for (int c = tid; c < nR; c += 256) {
    double vc = rex[c]; int ic = ridx[c];
    int rank = 0;
    for (int c2 = 0; c2 < nR; ++c2) {
      double v2 = rex[c2];
      rank += (v2 > vc) || (v2 == vc && ridx[c2] < ic);
    }
    if (rank < rNeed) {
      int p = atomicAdd(&selCount, 1);
      vals[row * 64 + p] = (float)vc;
      idxs[row * 64 + p] = ic;
    }
  }
}

// ---------------------------------------------------------------------------
// Kernel 4: y[row] = b_dec + sum_j vals[j] * W_dec[idx[j], :]  (fp32)
// ---------------------------------------------------------------------------
__global__ __launch_bounds__(256) void decode_kernel(
    const float* __restrict__ vals, const int* __restrict__ idxs,
    const float* __restrict__ Wdec, const float* __restrict__ bdec,
    float* __restrict__ Y) {
  __shared__ float sv[TOPK];
  __shared__ int   si[TOPK];
  const int tid = threadIdx.x;
  const int row = blockIdx.x;
  if (tid < TOPK) { sv[tid] = vals[row * 64 + tid]; si[tid] = idxs[row * 64 + tid]; }
  __syncthreads();
  const int c0 = tid * 4;
  const float4 b = *(const float4*)&bdec[c0];
  float a0 = b.x, a1 = b.y, a2 = b.z, a3 = b.w;
#pragma unroll 4
  for (int j = 0; j < TOPK; ++j) {
    const float vj = sv[j];
    const float4 w = *(const float4*)&Wdec[(size_t)si[j] * D_MODEL + c0];
    a0 += vj * w.x;
    a1 += vj * w.y;
    a2 += vj * w.z;
    a3 += vj * w.w;
  }
  float4 o; o.x = a0; o.y = a1; o.z = a2; o.w = a3;
  *(float4*)&Y[(size_t)row * D_MODEL + c0] = o;
}

// ---------------------------------------------------------------------------
extern "C" void kernel_launch(void* const* d_in, const int* in_sizes, int n_in,
                              void* d_out, int out_size, void* d_ws, size_t ws_size,
                              hipStream_t stream) {
  const float* x     = (const float*)d_in[0];
  const float* W_enc = (const float*)d_in[1];
  const float* b_enc = (const float*)d_in[2];
  const float* W_dec = (const float*)d_in[3];
  const float* b_dec = (const float*)d_in[4];

  const size_t WT_BYTES  = (size_t)D_HIDDEN * D_MODEL * sizeof(ushort_t); // 32 MB
  const size_t WT32_BYTES= (size_t)D_HIDDEN * D_MODEL * sizeof(float);    // 64 MB
  const size_t XB_BYTES  = (size_t)N_TOKENS * D_MODEL * sizeof(ushort_t); //  8 MB
  const size_t V_BYTES   = (size_t)N_TOKENS * TOPK * sizeof(float);       //  1 MB
  const size_t FIXED     = WT_BYTES + WT32_BYTES + XB_BYTES + 2 * V_BYTES;// 106 MB

  int chunk_rows = 512;  // 32 MB Z-chunk; total ~138 MB
  while (chunk_rows > 128 &&
         FIXED + (size_t)chunk_rows * D_HIDDEN * sizeof(float) > ws_size)
    chunk_rows >>= 1;

  char* ws = (char*)d_ws;
  ushort_t* WT   = (ushort_t*)ws;
  float*    WT32 = (float*)(ws + WT_BYTES);
  ushort_t* XB   = (ushort_t*)(ws + WT_BYTES + WT32_BYTES);
  float*    vals = (float*)(ws + WT_BYTES + WT32_BYTES + XB_BYTES);
  int*      idxs = (int*)(ws + WT_BYTES + WT32_BYTES + XB_BYTES + V_BYTES);
  float*    Z    = (float*)(ws + FIXED);
  float*    Y    = (float*)d_out;

  cast_x_kernel<<<dim3(N_TOKENS * D_MODEL / 1024), 256, 0, stream>>>(x, XB);
  transpose_cast_kernel<<<dim3(D_HIDDEN / 64, D_MODEL / 64), 256, 0, stream>>>(
      W_enc, WT, WT32);

  for (int r0 = 0; r0 < N_TOKENS; r0 += chunk_rows) {
    encode_gemm<<<dim3(D_HIDDEN / 128, chunk_rows / 128), 256, 0, stream>>>(
        XB + (size_t)r0 * D_MODEL, WT, b_enc, Z);
    topk_refine_kernel<<<dim3(chunk_rows), 256, 0, stream>>>(
        Z, x + (size_t)r0 * D_MODEL, WT32, b_enc,
        vals + (size_t)r0 * TOPK, idxs + (size_t)r0 * TOPK);
  }

  decode_kernel<<<dim3(N_TOKENS), 256, 0, stream>>>(vals, idxs, W_dec, b_dec, Y);
}

// Round 5
// 741.453 us; speedup vs baseline: 1.1828x; 1.1828x over previous
//
#include <hip/hip_runtime.h>

typedef unsigned short ushort_t;
typedef unsigned short ushort8 __attribute__((ext_vector_type(8)));
typedef __bf16 bf16x8 __attribute__((ext_vector_type(8)));
typedef float f32x4 __attribute__((ext_vector_type(4)));

#define N_TOKENS 4096
#define D_MODEL  1024
#define D_HIDDEN 16384
#define TOPK     64
#define DELTA    0.03f   // >= 2*E, E = bf16-GEMM err (~5e-3) + bf16-Z quant (~4e-3)
#define RCAP     128     // max refine candidates per row (expect ~20)

__device__ __forceinline__ float bf2f(ushort_t u) {
  union { unsigned u; float f; } c; c.u = ((unsigned)u) << 16; return c.f;
}
__device__ __forceinline__ ushort_t f2bf(float f) {
  union { float f; unsigned u; } c; c.f = f;
  unsigned x = c.u;
  unsigned r = (x + 0x7FFFu + ((x >> 16) & 1u)) >> 16;  // RNE
  return (ushort_t)r;
}

typedef __attribute__((address_space(1))) void GV;
typedef __attribute__((address_space(3))) void LV;
__device__ __forceinline__ void llds16(const void* g, void* l) {
  __builtin_amdgcn_global_load_lds((GV*)g, (LV*)l, 16, 0, 0);
}

// ---------------------------------------------------------------------------
// Kernel 0: cast x fp32 -> bf16
// ---------------------------------------------------------------------------
__global__ __launch_bounds__(256) void cast_x_kernel(
    const float* __restrict__ in, ushort_t* __restrict__ out) {
  const int i = (blockIdx.x * 256 + threadIdx.x) * 4;
  float4 v = *(const float4*)&in[i];
  ushort4 o;
  o.x = f2bf(v.x); o.y = f2bf(v.y); o.z = f2bf(v.z); o.w = f2bf(v.w);
  *(ushort4*)&out[i] = o;
}

// ---------------------------------------------------------------------------
// Kernel 0b: cast W_dec fp32 [H][K] -> bf16 (written into the WT buffer AFTER
// the last encode_gemm has consumed WT; stream order guarantees safety)
// ---------------------------------------------------------------------------
__global__ __launch_bounds__(256) void cast_wdec_kernel(
    const float* __restrict__ in, ushort_t* __restrict__ out) {
  const int i = (blockIdx.x * 256 + threadIdx.x) * 8;
  float4 v0 = *(const float4*)&in[i];
  float4 v1 = *(const float4*)&in[i + 4];
  ushort8 o;
  o[0] = f2bf(v0.x); o[1] = f2bf(v0.y); o[2] = f2bf(v0.z); o[3] = f2bf(v0.w);
  o[4] = f2bf(v1.x); o[5] = f2bf(v1.y); o[6] = f2bf(v1.z); o[7] = f2bf(v1.w);
  *(ushort8*)&out[i] = o;
}

// ---------------------------------------------------------------------------
// Kernel 1: W_enc fp32 [D_MODEL][D_HIDDEN] -> bf16 WT [H][K] + fp32 WT32 [H][K]
// ---------------------------------------------------------------------------
__global__ __launch_bounds__(256) void transpose_cast_kernel(
    const float* __restrict__ in, ushort_t* __restrict__ outb,
    float* __restrict__ out32) {
  __shared__ float tile[64][68];
  const int tid = threadIdx.x;
  const int n0 = blockIdx.x * 64;
  const int k0 = blockIdx.y * 64;
#pragma unroll
  for (int i = 0; i < 4; ++i) {
    int e = i * 256 + tid;
    int kk = e >> 4;
    int nn = (e & 15) * 4;
    float4 v = *(const float4*)&in[(size_t)(k0 + kk) * D_HIDDEN + n0 + nn];
    tile[kk][nn + 0] = v.x;
    tile[kk][nn + 1] = v.y;
    tile[kk][nn + 2] = v.z;
    tile[kk][nn + 3] = v.w;
  }
  __syncthreads();
#pragma unroll
  for (int i = 0; i < 4; ++i) {
    int e = i * 256 + tid;
    int nn = e >> 4;
    int kk = (e & 15) * 4;
    float4 f;
    f.x = tile[kk + 0][nn];
    f.y = tile[kk + 1][nn];
    f.z = tile[kk + 2][nn];
    f.w = tile[kk + 3][nn];
    *(float4*)&out32[(size_t)(n0 + nn) * D_MODEL + k0 + kk] = f;
    ushort4 b;
    b.x = f2bf(f.x); b.y = f2bf(f.y); b.z = f2bf(f.z); b.w = f2bf(f.w);
    *(ushort4*)&outb[(size_t)(n0 + nn) * D_MODEL + k0 + kk] = b;
  }
}

// ---------------------------------------------------------------------------
// Kernel 2: Z~ = relu(x @ W_enc + b_enc), bf16 out.  m97-style 128x128xBK32.
// ---------------------------------------------------------------------------
__global__ __launch_bounds__(256) void encode_gemm(
    const ushort_t* __restrict__ X, const ushort_t* __restrict__ WT,
    const float* __restrict__ benc, ushort_t* __restrict__ Z) {
  __shared__ ushort_t As[128 * 32];
  __shared__ ushort_t Bs[128 * 32];
  const int tid  = threadIdx.x;
  const int wave = tid >> 6, lane = tid & 63;
  const int m0 = blockIdx.y * 128;
  const int n0 = blockIdx.x * 128;
  const int wm = (wave >> 1) * 64;
  const int wn = (wave & 1) * 64;
  const int lr = lane >> 2;
  const int lk = (lane & 3) * 8;

  f32x4 acc[4][4];
#pragma unroll
  for (int i = 0; i < 4; ++i)
#pragma unroll
    for (int j = 0; j < 4; ++j) acc[i][j] = (f32x4){0.f, 0.f, 0.f, 0.f};

  for (int k0 = 0; k0 < D_MODEL; k0 += 32) {
    __syncthreads();
#pragma unroll
    for (int c = 0; c < 2; ++c) {
      const int chunk = c * 4 + wave;
      const int m = chunk * 16 + lr;
      llds16(&X [(size_t)(m0 + m) * D_MODEL + k0 + lk], &As[chunk * 512]);
      llds16(&WT[(size_t)(n0 + m) * D_MODEL + k0 + lk], &Bs[chunk * 512]);
    }
    __syncthreads();
    bf16x8 af[4], bfr[4];
#pragma unroll
    for (int t = 0; t < 4; ++t) {
      af[t]  = *(const bf16x8*)&As[(wm + t * 16 + (lane & 15)) * 32 + (lane >> 4) * 8];
      bfr[t] = *(const bf16x8*)&Bs[(wn + t * 16 + (lane & 15)) * 32 + (lane >> 4) * 8];
    }
#pragma unroll
    for (int mt = 0; mt < 4; ++mt)
#pragma unroll
      for (int nt = 0; nt < 4; ++nt)
        acc[mt][nt] = __builtin_amdgcn_mfma_f32_16x16x32_bf16(
            af[mt], bfr[nt], acc[mt][nt], 0, 0, 0);
  }

  const int col_base = n0 + wn + (lane & 15);
  const int row_base = m0 + wm + (lane >> 4) * 4;
#pragma unroll
  for (int nt = 0; nt < 4; ++nt) {
    const float bias = benc[col_base + nt * 16];
#pragma unroll
    for (int mt = 0; mt < 4; ++mt) {
#pragma unroll
      for (int r = 0; r < 4; ++r) {
        float v = fmaxf(acc[mt][nt][r] + bias, 0.0f);
        Z[(size_t)(row_base + mt * 16 + r) * D_HIDDEN + col_base + nt * 16] = f2bf(v);
      }
    }
  }
}

// ---------------------------------------------------------------------------
// Kernel 3: top-64 with exact fp64 boundary resolution (Z in bf16).
// ---------------------------------------------------------------------------
__global__ __launch_bounds__(256) void topk_refine_kernel(
    const ushort_t* __restrict__ Z, const float* __restrict__ x32,
    const float* __restrict__ WT32, const float* __restrict__ benc,
    float* __restrict__ vals, int* __restrict__ idxs) {
  __shared__ int    hist[2048];
  __shared__ float  cval[1024];
  __shared__ int    cidx[1024];
  __shared__ int    tsum[256], suff[256];
  __shared__ float  xrow[1024];
  __shared__ int    ridx[RCAP];
  __shared__ double rex[RCAP];
  __shared__ double redpart[RCAP * 4];
  __shared__ int    sTbin, sAbove, selCount, candCount, refCount;
  __shared__ float  sV64;
  const int tid  = threadIdx.x;
  const int wave = tid >> 6, lane = tid & 63;
  const int row  = blockIdx.x;
  const ushort_t* zr = Z + (size_t)row * D_HIDDEN;

  // vectorized bf16 load: thread covers 8 contiguous elems in 8 strips
  float v[64];
#pragma unroll
  for (int i = 0; i < 8; ++i) {
    ushort8 w = *(const ushort8*)&zr[i * 2048 + tid * 8];
#pragma unroll
    for (int u = 0; u < 8; ++u) v[i * 8 + u] = bf2f(w[u]);
  }
  // global index of v[i]: (i>>3)*2048 + tid*8 + (i&7)
#define VIDX(i) (((i) >> 3) * 2048 + tid * 8 + ((i) & 7))

  *(float4*)&xrow[tid * 4] = *(const float4*)&x32[(size_t)row * D_MODEL + tid * 4];
#pragma unroll
  for (int i = 0; i < 8; ++i) hist[tid * 8 + i] = 0;
  if (tid == 0) { selCount = 0; candCount = 0; refCount = 0; }
  __syncthreads();
#pragma unroll
  for (int i = 0; i < 64; ++i)
    atomicAdd(&hist[__float_as_uint(v[i]) >> 20], 1);
  __syncthreads();
  int s = 0;
#pragma unroll
  for (int i = 0; i < 8; ++i) s += hist[tid * 8 + i];
  tsum[tid] = s;
  __syncthreads();
  if (tid == 0) {
    int run = 0;
    for (int t = 255; t >= 0; --t) { suff[t] = run; run += tsum[t]; }
  }
  __syncthreads();
  {
    int cum = suff[tid];
    for (int key = tid * 8 + 7; key >= tid * 8; --key) {
      int h = hist[key];
      if (cum < TOPK && cum + h >= TOPK) { sTbin = key; sAbove = cum; }
      cum += h;
    }
  }
  __syncthreads();
  const int Tbin = sTbin, nAbove = sAbove;

  if (Tbin == 0) {  // degenerate: <64 positive activations
#pragma unroll
    for (int i = 0; i < 64; ++i) {
      if ((int)(__float_as_uint(v[i]) >> 20) > 0) {
        int p = atomicAdd(&selCount, 1);
        if (p < TOPK) { vals[row * 64 + p] = v[i]; idxs[row * 64 + p] = VIDX(i); }
      }
    }
    __syncthreads();
    for (int p2 = min(selCount, TOPK) + tid; p2 < TOPK; p2 += 256) {
      vals[row * 64 + p2] = 0.0f; idxs[row * 64 + p2] = 0;
    }
    return;
  }

  // Phase B: exact z~ 64th value
#pragma unroll
  for (int i = 0; i < 64; ++i) {
    if ((int)(__float_as_uint(v[i]) >> 20) == Tbin) {
      int c = atomicAdd(&candCount, 1);
      if (c < 1024) { cval[c] = v[i]; cidx[c] = VIDX(i); }
    }
  }
  __syncthreads();
  {
    const int r  = TOPK - nAbove;
    const int nc = min(candCount, 1024);
    for (int j = tid; j < nc; j += 256) {
      float vj = cval[j]; int ij = cidx[j];
      int rank = 0;
      for (int j2 = 0; j2 < nc; ++j2) {
        float v2 = cval[j2];
        rank += (v2 > vj) || (v2 == vj && cidx[j2] < ij);
      }
      if (rank == r - 1) sV64 = vj;
    }
  }
  __syncthreads();
  const float v64 = sV64;

  // Phase C: classify
#pragma unroll
  for (int i = 0; i < 64; ++i) {
    if (v[i] > v64 + DELTA) {
      int p = atomicAdd(&selCount, 1);
      vals[row * 64 + p] = v[i];
      idxs[row * 64 + p] = VIDX(i);
    } else if (v[i] >= v64 - DELTA) {
      int c = atomicAdd(&refCount, 1);
      if (c < RCAP) ridx[c] = VIDX(i);
    }
  }
  __syncthreads();
  const int nS = selCount;
  const int nR = min(refCount, RCAP);
  const int rNeed = TOPK - nS;

  // Phase D: exact fp64 dots for refine candidates
  for (int c = 0; c < nR; ++c) {
    const int j = ridx[c];
    const float* wr = &WT32[(size_t)j * D_MODEL];
    double part = 0.0;
#pragma unroll
    for (int u = 0; u < 4; ++u)
      part += (double)xrow[tid * 4 + u] * (double)wr[tid * 4 + u];
#pragma unroll
    for (int off = 32; off > 0; off >>= 1) part += __shfl_down(part, off, 64);
    if (lane == 0) redpart[c * 4 + wave] = part;
  }
  __syncthreads();
  for (int c = tid; c < nR; c += 256) {
    double d = redpart[c * 4] + redpart[c * 4 + 1] + redpart[c * 4 + 2] + redpart[c * 4 + 3];
    d += (double)benc[ridx[c]];
    rex[c] = d > 0.0 ? d : 0.0;
  }
  __syncthreads();

  // Phase E: rank refined by (value desc, index asc), take top rNeed
  for (int c = tid; c < nR; c += 256) {
    double vc = rex[c]; int ic = ridx[c];
    int rank = 0;
    for (int c2 = 0; c2 < nR; ++c2) {
      double v2 = rex[c2];
      rank += (v2 > vc) || (v2 == vc && ridx[c2] < ic);
    }
    if (rank < rNeed) {
      int p = atomicAdd(&selCount, 1);
      vals[row * 64 + p] = (float)vc;
      idxs[row * 64 + p] = ic;
    }
  }
}

// ---------------------------------------------------------------------------
// Kernel 4: y = b_dec + sum_j vals[j]*W_dec[idx[j],:]  (bf16 W_dec gathers,
// fp32 accumulate/out). 2 tokens per block, 128 threads x 8 cols each.
// ---------------------------------------------------------------------------
__global__ __launch_bounds__(256) void decode_kernel(
    const float* __restrict__ vals, const int* __restrict__ idxs,
    const ushort_t* __restrict__ Wdec_bf, const float* __restrict__ bdec,
    float* __restrict__ Y) {
  __shared__ float sv[2][TOPK];
  __shared__ int   si[2][TOPK];
  const int tid = threadIdx.x;
  const int r0  = blockIdx.x * 2;
  if (tid < 128) {
    int rr = tid >> 6, jj = tid & 63;
    sv[rr][jj] = vals[(r0 + rr) * 64 + jj];
    si[rr][jj] = idxs[(r0 + rr) * 64 + jj];
  }
  __syncthreads();
  const int rr  = tid >> 7;
  const int c0  = (tid & 127) * 8;
  const int row = r0 + rr;
  float4 b0 = *(const float4*)&bdec[c0];
  float4 b1 = *(const float4*)&bdec[c0 + 4];
  float a[8] = {b0.x, b0.y, b0.z, b0.w, b1.x, b1.y, b1.z, b1.w};
#pragma unroll 8
  for (int j = 0; j < TOPK; ++j) {
    const float vj = sv[rr][j];
    ushort8 w = *(const ushort8*)&Wdec_bf[(size_t)si[rr][j] * D_MODEL + c0];
#pragma unroll
    for (int u = 0; u < 8; ++u) a[u] += vj * bf2f(w[u]);
  }
  *(float4*)&Y[(size_t)row * D_MODEL + c0]     = (float4){a[0], a[1], a[2], a[3]};
  *(float4*)&Y[(size_t)row * D_MODEL + c0 + 4] = (float4){a[4], a[5], a[6], a[7]};
}

// ---------------------------------------------------------------------------
extern "C" void kernel_launch(void* const* d_in, const int* in_sizes, int n_in,
                              void* d_out, int out_size, void* d_ws, size_t ws_size,
                              hipStream_t stream) {
  const float* x     = (const float*)d_in[0];
  const float* W_enc = (const float*)d_in[1];
  const float* b_enc = (const float*)d_in[2];
  const float* W_dec = (const float*)d_in[3];
  const float* b_dec = (const float*)d_in[4];

  const size_t WT_BYTES   = (size_t)D_HIDDEN * D_MODEL * sizeof(ushort_t); // 32 MB (WT, later W_dec bf16)
  const size_t WT32_BYTES = (size_t)D_HIDDEN * D_MODEL * sizeof(float);    // 64 MB
  const size_t XB_BYTES   = (size_t)N_TOKENS * D_MODEL * sizeof(ushort_t); //  8 MB
  const size_t V_BYTES    = (size_t)N_TOKENS * TOPK * sizeof(float);       //  1 MB
  const size_t FIXED      = WT_BYTES + WT32_BYTES + XB_BYTES + 2 * V_BYTES;// 106 MB

  int chunk_rows = 4096;  // bf16 Z chunk: 128 MB -> total 234 MB; auto-shrink
  while (chunk_rows > 128 &&
         FIXED + (size_t)chunk_rows * D_HIDDEN * sizeof(ushort_t) > ws_size)
    chunk_rows >>= 1;

  char* ws = (char*)d_ws;
  ushort_t* WT   = (ushort_t*)ws;              // bf16 W_enc^T, then bf16 W_dec
  float*    WT32 = (float*)(ws + WT_BYTES);
  ushort_t* XB   = (ushort_t*)(ws + WT_BYTES + WT32_BYTES);
  float*    vals = (float*)(ws + WT_BYTES + WT32_BYTES + XB_BYTES);
  int*      idxs = (int*)(ws + WT_BYTES + WT32_BYTES + XB_BYTES + V_BYTES);
  ushort_t* Z    = (ushort_t*)(ws + FIXED);
  float*    Y    = (float*)d_out;

  cast_x_kernel<<<dim3(N_TOKENS * D_MODEL / 1024), 256, 0, stream>>>(x, XB);
  transpose_cast_kernel<<<dim3(D_HIDDEN / 64, D_MODEL / 64), 256, 0, stream>>>(
      W_enc, WT, WT32);

  for (int r0 = 0; r0 < N_TOKENS; r0 += chunk_rows) {
    encode_gemm<<<dim3(D_HIDDEN / 128, chunk_rows / 128), 256, 0, stream>>>(
        XB + (size_t)r0 * D_MODEL, WT, b_enc, Z);
    topk_refine_kernel<<<dim3(chunk_rows), 256, 0, stream>>>(
        Z, x + (size_t)r0 * D_MODEL, WT32, b_enc,
        vals + (size_t)r0 * TOPK, idxs + (size_t)r0 * TOPK);
  }

  // cast W_dec -> bf16 into the WT buffer (all encode_gemm reads of WT are done)
  cast_wdec_kernel<<<dim3(D_HIDDEN * D_MODEL / (256 * 8)), 256, 0, stream>>>(W_dec, WT);

  decode_kernel<<<dim3(N_TOKENS / 2), 256, 0, stream>>>(vals, idxs, WT, b_dec, Y);
}

// Round 6
// 556.202 us; speedup vs baseline: 1.5767x; 1.3331x over previous
//
#include <hip/hip_runtime.h>

typedef unsigned short ushort_t;
typedef unsigned short ushort8 __attribute__((ext_vector_type(8)));
typedef __bf16 bf16x8 __attribute__((ext_vector_type(8)));
typedef float f32x4 __attribute__((ext_vector_type(4)));

#define N_TOKENS 4096
#define D_MODEL  1024
#define D_HIDDEN 16384
#define TOPK     64
#define DELTA    0.03f   // >= 2*E, E = bf16-GEMM err (~5e-3) + bf16-Z quant (~4e-3)
#define RCAP     128     // max refine candidates per row (expect ~40)

__device__ __forceinline__ float bf2f(ushort_t u) {
  union { unsigned u; float f; } c; c.u = ((unsigned)u) << 16; return c.f;
}
__device__ __forceinline__ ushort_t f2bf(float f) {
  union { float f; unsigned u; } c; c.f = f;
  unsigned x = c.u;
  unsigned r = (x + 0x7FFFu + ((x >> 16) & 1u)) >> 16;  // RNE
  return (ushort_t)r;
}

typedef __attribute__((address_space(1))) void GV;
typedef __attribute__((address_space(3))) void LV;
__device__ __forceinline__ void llds16(const void* g, void* l) {
  __builtin_amdgcn_global_load_lds((GV*)g, (LV*)l, 16, 0, 0);
}

// ---------------------------------------------------------------------------
// Kernel 0: cast x fp32 -> bf16
// ---------------------------------------------------------------------------
__global__ __launch_bounds__(256) void cast_x_kernel(
    const float* __restrict__ in, ushort_t* __restrict__ out) {
  const int i = (blockIdx.x * 256 + threadIdx.x) * 4;
  float4 v = *(const float4*)&in[i];
  ushort4 o;
  o.x = f2bf(v.x); o.y = f2bf(v.y); o.z = f2bf(v.z); o.w = f2bf(v.w);
  *(ushort4*)&out[i] = o;
}

// ---------------------------------------------------------------------------
// Kernel 0b: cast W_dec fp32 [H][K] -> bf16 (into WT buffer after last GEMM)
// ---------------------------------------------------------------------------
__global__ __launch_bounds__(256) void cast_wdec_kernel(
    const float* __restrict__ in, ushort_t* __restrict__ out) {
  const int i = (blockIdx.x * 256 + threadIdx.x) * 8;
  float4 v0 = *(const float4*)&in[i];
  float4 v1 = *(const float4*)&in[i + 4];
  ushort8 o;
  o[0] = f2bf(v0.x); o[1] = f2bf(v0.y); o[2] = f2bf(v0.z); o[3] = f2bf(v0.w);
  o[4] = f2bf(v1.x); o[5] = f2bf(v1.y); o[6] = f2bf(v1.z); o[7] = f2bf(v1.w);
  *(ushort8*)&out[i] = o;
}

// ---------------------------------------------------------------------------
// Kernel 1: W_enc fp32 [D_MODEL][D_HIDDEN] -> bf16 WT [H][K] + fp32 WT32 [H][K]
// ---------------------------------------------------------------------------
__global__ __launch_bounds__(256) void transpose_cast_kernel(
    const float* __restrict__ in, ushort_t* __restrict__ outb,
    float* __restrict__ out32) {
  __shared__ float tile[64][68];
  const int tid = threadIdx.x;
  const int n0 = blockIdx.x * 64;
  const int k0 = blockIdx.y * 64;
#pragma unroll
  for (int i = 0; i < 4; ++i) {
    int e = i * 256 + tid;
    int kk = e >> 4;
    int nn = (e & 15) * 4;
    float4 v = *(const float4*)&in[(size_t)(k0 + kk) * D_HIDDEN + n0 + nn];
    tile[kk][nn + 0] = v.x;
    tile[kk][nn + 1] = v.y;
    tile[kk][nn + 2] = v.z;
    tile[kk][nn + 3] = v.w;
  }
  __syncthreads();
#pragma unroll
  for (int i = 0; i < 4; ++i) {
    int e = i * 256 + tid;
    int nn = e >> 4;
    int kk = (e & 15) * 4;
    float4 f;
    f.x = tile[kk + 0][nn];
    f.y = tile[kk + 1][nn];
    f.z = tile[kk + 2][nn];
    f.w = tile[kk + 3][nn];
    *(float4*)&out32[(size_t)(n0 + nn) * D_MODEL + k0 + kk] = f;
    ushort4 b;
    b.x = f2bf(f.x); b.y = f2bf(f.y); b.z = f2bf(f.z); b.w = f2bf(f.w);
    *(ushort4*)&outb[(size_t)(n0 + nn) * D_MODEL + k0 + kk] = b;
  }
}

// ---------------------------------------------------------------------------
// Kernel 2: Z~ = relu(x @ W_enc + b_enc), bf16 out.  m97-style 128x128xBK32.
// ---------------------------------------------------------------------------
__global__ __launch_bounds__(256) void encode_gemm(
    const ushort_t* __restrict__ X, const ushort_t* __restrict__ WT,
    const float* __restrict__ benc, ushort_t* __restrict__ Z) {
  __shared__ ushort_t As[128 * 32];
  __shared__ ushort_t Bs[128 * 32];
  const int tid  = threadIdx.x;
  const int wave = tid >> 6, lane = tid & 63;
  const int m0 = blockIdx.y * 128;
  const int n0 = blockIdx.x * 128;
  const int wm = (wave >> 1) * 64;
  const int wn = (wave & 1) * 64;
  const int lr = lane >> 2;
  const int lk = (lane & 3) * 8;

  f32x4 acc[4][4];
#pragma unroll
  for (int i = 0; i < 4; ++i)
#pragma unroll
    for (int j = 0; j < 4; ++j) acc[i][j] = (f32x4){0.f, 0.f, 0.f, 0.f};

  for (int k0 = 0; k0 < D_MODEL; k0 += 32) {
    __syncthreads();
#pragma unroll
    for (int c = 0; c < 2; ++c) {
      const int chunk = c * 4 + wave;
      const int m = chunk * 16 + lr;
      llds16(&X [(size_t)(m0 + m) * D_MODEL + k0 + lk], &As[chunk * 512]);
      llds16(&WT[(size_t)(n0 + m) * D_MODEL + k0 + lk], &Bs[chunk * 512]);
    }
    __syncthreads();
    bf16x8 af[4], bfr[4];
#pragma unroll
    for (int t = 0; t < 4; ++t) {
      af[t]  = *(const bf16x8*)&As[(wm + t * 16 + (lane & 15)) * 32 + (lane >> 4) * 8];
      bfr[t] = *(const bf16x8*)&Bs[(wn + t * 16 + (lane & 15)) * 32 + (lane >> 4) * 8];
    }
#pragma unroll
    for (int mt = 0; mt < 4; ++mt)
#pragma unroll
      for (int nt = 0; nt < 4; ++nt)
        acc[mt][nt] = __builtin_amdgcn_mfma_f32_16x16x32_bf16(
            af[mt], bfr[nt], acc[mt][nt], 0, 0, 0);
  }

  const int col_base = n0 + wn + (lane & 15);
  const int row_base = m0 + wm + (lane >> 4) * 4;
#pragma unroll
  for (int nt = 0; nt < 4; ++nt) {
    const float bias = benc[col_base + nt * 16];
#pragma unroll
    for (int mt = 0; mt < 4; ++mt) {
#pragma unroll
      for (int r = 0; r < 4; ++r) {
        float v = fmaxf(acc[mt][nt][r] + bias, 0.0f);
        Z[(size_t)(row_base + mt * 16 + r) * D_HIDDEN + col_base + nt * 16] = f2bf(v);
      }
    }
  }
}

// ---------------------------------------------------------------------------
// Kernel 3: top-64 with exact fp64 boundary resolution (Z in bf16).
// R6: histogram only hashes v>0 (kills bin-0 atomic pile-up);
//     Phase D wave-per-candidate (coalesced row reads, in-wave reduce).
// ---------------------------------------------------------------------------
__global__ __launch_bounds__(256) void topk_refine_kernel(
    const ushort_t* __restrict__ Z, const float* __restrict__ x32,
    const float* __restrict__ WT32, const float* __restrict__ benc,
    float* __restrict__ vals, int* __restrict__ idxs) {
  __shared__ int    hist[2048];
  __shared__ float  cval[1024];
  __shared__ int    cidx[1024];
  __shared__ int    tsum[256], suff[256];
  __shared__ float  xrow[1024];
  __shared__ int    ridx[RCAP];
  __shared__ double rex[RCAP];
  __shared__ int    sTbin, sAbove, selCount, candCount, refCount;
  __shared__ float  sV64;
  const int tid  = threadIdx.x;
  const int wave = tid >> 6, lane = tid & 63;
  const int row  = blockIdx.x;
  const ushort_t* zr = Z + (size_t)row * D_HIDDEN;

  float v[64];
#pragma unroll
  for (int i = 0; i < 8; ++i) {
    ushort8 w = *(const ushort8*)&zr[i * 2048 + tid * 8];
#pragma unroll
    for (int u = 0; u < 8; ++u) v[i * 8 + u] = bf2f(w[u]);
  }
#define VIDX(i) (((i) >> 3) * 2048 + tid * 8 + ((i) & 7))

  *(float4*)&xrow[tid * 4] = *(const float4*)&x32[(size_t)row * D_MODEL + tid * 4];
#pragma unroll
  for (int i = 0; i < 8; ++i) hist[tid * 8 + i] = 0;
  if (tid == 0) { sTbin = -1; selCount = 0; candCount = 0; refCount = 0; }
  __syncthreads();
  // Phase A: histogram of POSITIVE values only (top-12 bits of fp32)
#pragma unroll
  for (int i = 0; i < 64; ++i)
    if (v[i] > 0.0f) atomicAdd(&hist[__float_as_uint(v[i]) >> 20], 1);
  __syncthreads();
  int s = 0;
#pragma unroll
  for (int i = 0; i < 8; ++i) s += hist[tid * 8 + i];
  tsum[tid] = s;
  __syncthreads();
  if (tid == 0) {
    int run = 0;
    for (int t = 255; t >= 0; --t) { suff[t] = run; run += tsum[t]; }
  }
  __syncthreads();
  {
    int cum = suff[tid];
    for (int key = tid * 8 + 7; key >= tid * 8; --key) {
      int h = hist[key];
      if (cum < TOPK && cum + h >= TOPK) { sTbin = key; sAbove = cum; }
      cum += h;
    }
  }
  __syncthreads();
  const int Tbin = sTbin, nAbove = sAbove;

  if (Tbin < 0) {  // degenerate: fewer than 64 positive activations
#pragma unroll
    for (int i = 0; i < 64; ++i) {
      if (v[i] > 0.0f) {
        int p = atomicAdd(&selCount, 1);
        if (p < TOPK) { vals[row * 64 + p] = v[i]; idxs[row * 64 + p] = VIDX(i); }
      }
    }
    __syncthreads();
    for (int p2 = min(selCount, TOPK) + tid; p2 < TOPK; p2 += 256) {
      vals[row * 64 + p2] = 0.0f; idxs[row * 64 + p2] = 0;
    }
    return;
  }

  // Phase B: exact z~ 64th value (in-bin rank by value desc, index asc)
#pragma unroll
  for (int i = 0; i < 64; ++i) {
    if (v[i] > 0.0f && (int)(__float_as_uint(v[i]) >> 20) == Tbin) {
      int c = atomicAdd(&candCount, 1);
      if (c < 1024) { cval[c] = v[i]; cidx[c] = VIDX(i); }
    }
  }
  __syncthreads();
  {
    const int r  = TOPK - nAbove;
    const int nc = min(candCount, 1024);
    for (int j = tid; j < nc; j += 256) {
      float vj = cval[j]; int ij = cidx[j];
      int rank = 0;
      for (int j2 = 0; j2 < nc; ++j2) {
        float v2 = cval[j2];
        rank += (v2 > vj) || (v2 == vj && cidx[j2] < ij);
      }
      if (rank == r - 1) sV64 = vj;
    }
  }
  __syncthreads();
  const float v64 = sV64;

  // Phase C: classify
#pragma unroll
  for (int i = 0; i < 64; ++i) {
    if (v[i] > v64 + DELTA) {
      int p = atomicAdd(&selCount, 1);
      vals[row * 64 + p] = v[i];
      idxs[row * 64 + p] = VIDX(i);
    } else if (v[i] >= v64 - DELTA) {
      int c = atomicAdd(&refCount, 1);
      if (c < RCAP) ridx[c] = VIDX(i);
    }
  }
  __syncthreads();
  const int nS = selCount;
  const int nR = min(refCount, RCAP);
  const int rNeed = TOPK - nS;

  // Phase D: exact fp64 dots, ONE WAVE PER CANDIDATE (lane covers 16 cols)
  float xr[16];
#pragma unroll
  for (int q = 0; q < 16; ++q) xr[q] = xrow[lane * 16 + q];
  for (int c = wave; c < nR; c += 4) {
    const int j = ridx[c];
    const float* wr = &WT32[(size_t)j * D_MODEL];
    double p0 = 0.0, p1 = 0.0;
#pragma unroll
    for (int q = 0; q < 2; ++q) {
      const float4 wa = *(const float4*)&wr[lane * 16 + q * 8];
      const float4 wb = *(const float4*)&wr[lane * 16 + q * 8 + 4];
      p0 += (double)xr[q * 8 + 0] * wa.x + (double)xr[q * 8 + 1] * wa.y
          + (double)xr[q * 8 + 2] * wa.z + (double)xr[q * 8 + 3] * wa.w;
      p1 += (double)xr[q * 8 + 4] * wb.x + (double)xr[q * 8 + 5] * wb.y
          + (double)xr[q * 8 + 6] * wb.z + (double)xr[q * 8 + 7] * wb.w;
    }
    double part = p0 + p1;
#pragma unroll
    for (int off = 32; off > 0; off >>= 1) part += __shfl_down(part, off, 64);
    if (lane == 0) {
      double d = part + (double)benc[j];
      rex[c] = d > 0.0 ? d : 0.0;
    }
  }
  __syncthreads();

  // Phase E: rank refined by (value desc, index asc), take top rNeed
  for (int c = tid; c < nR; c += 256) {
    double vc = rex[c]; int ic = ridx[c];
    int rank = 0;
    for (int c2 = 0; c2 < nR; ++c2) {
      double v2 = rex[c2];
      rank += (v2 > vc) || (v2 == vc && ridx[c2] < ic);
    }
    if (rank < rNeed) {
      int p = atomicAdd(&selCount, 1);
      vals[row * 64 + p] = (float)vc;
      idxs[row * 64 + p] = ic;
    }
  }
}

// ---------------------------------------------------------------------------
// Kernel 4: y = b_dec + sum_j vals[j]*W_dec[idx[j],:]  (bf16 gathers, fp32 out)
// ---------------------------------------------------------------------------
__global__ __launch_bounds__(256) void decode_kernel(
    const float* __restrict__ vals, const int* __restrict__ idxs,
    const ushort_t* __restrict__ Wdec_bf, const float* __restrict__ bdec,
    float* __restrict__ Y) {
  __shared__ float sv[2][TOPK];
  __shared__ int   si[2][TOPK];
  const int tid = threadIdx.x;
  const int r0  = blockIdx.x * 2;
  if (tid < 128) {
    int rr = tid >> 6, jj = tid & 63;
    sv[rr][jj] = vals[(r0 + rr) * 64 + jj];
    si[rr][jj] = idxs[(r0 + rr) * 64 + jj];
  }
  __syncthreads();
  const int rr  = tid >> 7;
  const int c0  = (tid & 127) * 8;
  const int row = r0 + rr;
  float4 b0 = *(const float4*)&bdec[c0];
  float4 b1 = *(const float4*)&bdec[c0 + 4];
  float a[8] = {b0.x, b0.y, b0.z, b0.w, b1.x, b1.y, b1.z, b1.w};
#pragma unroll 8
  for (int j = 0; j < TOPK; ++j) {
    const float vj = sv[rr][j];
    ushort8 w = *(const ushort8*)&Wdec_bf[(size_t)si[rr][j] * D_MODEL + c0];
#pragma unroll
    for (int u = 0; u < 8; ++u) a[u] += vj * bf2f(w[u]);
  }
  *(float4*)&Y[(size_t)row * D_MODEL + c0]     = (float4){a[0], a[1], a[2], a[3]};
  *(float4*)&Y[(size_t)row * D_MODEL + c0 + 4] = (float4){a[4], a[5], a[6], a[7]};
}

// ---------------------------------------------------------------------------
extern "C" void kernel_launch(void* const* d_in, const int* in_sizes, int n_in,
                              void* d_out, int out_size, void* d_ws, size_t ws_size,
                              hipStream_t stream) {
  const float* x     = (const float*)d_in[0];
  const float* W_enc = (const float*)d_in[1];
  const float* b_enc = (const float*)d_in[2];
  const float* W_dec = (const float*)d_in[3];
  const float* b_dec = (const float*)d_in[4];

  const size_t WT_BYTES   = (size_t)D_HIDDEN * D_MODEL * sizeof(ushort_t); // 32 MB
  const size_t WT32_BYTES = (size_t)D_HIDDEN * D_MODEL * sizeof(float);    // 64 MB
  const size_t XB_BYTES   = (size_t)N_TOKENS * D_MODEL * sizeof(ushort_t); //  8 MB
  const size_t V_BYTES    = (size_t)N_TOKENS * TOPK * sizeof(float);       //  1 MB
  const size_t FIXED      = WT_BYTES + WT32_BYTES + XB_BYTES + 2 * V_BYTES;// 106 MB

  int chunk_rows = 4096;  // bf16 Z chunk: 128 MB -> total 234 MB; auto-shrink
  while (chunk_rows > 128 &&
         FIXED + (size_t)chunk_rows * D_HIDDEN * sizeof(ushort_t) > ws_size)
    chunk_rows >>= 1;

  char* ws = (char*)d_ws;
  ushort_t* WT   = (ushort_t*)ws;              // bf16 W_enc^T, then bf16 W_dec
  float*    WT32 = (float*)(ws + WT_BYTES);
  ushort_t* XB   = (ushort_t*)(ws + WT_BYTES + WT32_BYTES);
  float*    vals = (float*)(ws + WT_BYTES + WT32_BYTES + XB_BYTES);
  int*      idxs = (int*)(ws + WT_BYTES + WT32_BYTES + XB_BYTES + V_BYTES);
  ushort_t* Z    = (ushort_t*)(ws + FIXED);
  float*    Y    = (float*)d_out;

  cast_x_kernel<<<dim3(N_TOKENS * D_MODEL / 1024), 256, 0, stream>>>(x, XB);
  transpose_cast_kernel<<<dim3(D_HIDDEN / 64, D_MODEL / 64), 256, 0, stream>>>(
      W_enc, WT, WT32);

  for (int r0 = 0; r0 < N_TOKENS; r0 += chunk_rows) {
    encode_gemm<<<dim3(D_HIDDEN / 128, chunk_rows / 128), 256, 0, stream>>>(
        XB + (size_t)r0 * D_MODEL, WT, b_enc, Z);
    topk_refine_kernel<<<dim3(chunk_rows), 256, 0, stream>>>(
        Z, x + (size_t)r0 * D_MODEL, WT32, b_enc,
        vals + (size_t)r0 * TOPK, idxs + (size_t)r0 * TOPK);
  }

  cast_wdec_kernel<<<dim3(D_HIDDEN * D_MODEL / (256 * 8)), 256, 0, stream>>>(W_dec, WT);

  decode_kernel<<<dim3(N_TOKENS / 2), 256, 0, stream>>>(vals, idxs, WT, b_dec, Y);
}